// Round 11
// baseline (951.282 us; speedup 1.0000x reference)
//
#include <hip/hip_runtime.h>
#include <math.h>

#define CAPT 20480              // per-type compacted-node capacity (actual ~16.7k)
#define R2   (2*CAPT)
#define GLD  136                // kgru LDS row stride (ushorts): breaks pow2 banking
#define GRR  32                 // kgru rows per block

typedef __attribute__((ext_vector_type(8))) short short8;
typedef __attribute__((ext_vector_type(4))) float f32x4;

// ---- fast transcendentals: v_exp_f32 / v_rcp_f32 based; err ~1e-7 << bf16 ulp ----
__device__ __forceinline__ float fexp2_(float x){ return __builtin_amdgcn_exp2f(x); }
__device__ __forceinline__ float frcp_(float x){ return __builtin_amdgcn_rcpf(x); }
__device__ __forceinline__ float ftanh_(float x){
  float ax = __builtin_fabsf(x);
  float t = fexp2_(-2.885390082f * ax);          // e^{-2|x|}
  float r = (1.f - t) * frcp_(1.f + t);
  return __builtin_copysignf(r, x);
}
__device__ __forceinline__ float fsig_(float x){
  return frcp_(1.f + fexp2_(-1.442695041f * x));
}
__device__ __forceinline__ float fgelu_(float x){
  const float c = 0.7978845608028654f;
  return 0.5f*x*(1.f + ftanh_(c*(x + 0.044715f*x*x*x)));
}
__device__ __forceinline__ unsigned short f2bf(float x){
  unsigned int u = __float_as_uint(x);
  return (unsigned short)((u + 0x7FFFu + ((u>>16)&1u)) >> 16);
}
__device__ __forceinline__ float bf2f(unsigned short v){
  return __uint_as_float(((unsigned int)v) << 16);
}

// ---------------- weight prep: transposed bf16 B arena, padded to 16-mult segments ----
// Arena layout (bf16 elems):
//  [0..6)      plain msg li:  [160][96]   off = li*15360
//  [6..12)     plain upd li:  [80][160]   off = 92160 + li*12800
//  [12..14)    ar msg blk:    [320][160]  off = 168960 + blk*51200
//  [14..16)    ar upd blk:    [80][320]   off = 271360 + blk*25600
//  [16..18)    gru typ:       [256][128]  off = 322560 + typ*32768
__global__ void k_prepB(const float* __restrict__ Wm_plain, const float* __restrict__ Wu_plain,
                        const float* __restrict__ Wm_ar, const float* __restrict__ Wu_ar,
                        const float* __restrict__ Wi_map, const float* __restrict__ Wh_map,
                        const float* __restrict__ Wi_mem, const float* __restrict__ Wh_mem,
                        unsigned short* __restrict__ BtArena){
  int id = blockIdx.y;
  int Kp, elems, off;
  if (id < 6){ Kp=96;  elems=15360; off=id*15360; }
  else if (id < 12){ Kp=160; elems=12800; off=92160+(id-6)*12800; }
  else if (id < 14){ Kp=160; elems=51200; off=168960+(id-12)*51200; }
  else if (id < 16){ Kp=320; elems=25600; off=271360+(id-14)*25600; }
  else { Kp=128; elems=32768; off=322560+(id-16)*32768; }
  for (int g = blockIdx.x*256 + threadIdx.x; g < elems; g += 8*256){
    int c = g / Kp, k = g - c*Kp;
    float val = 0.f;
    if (id < 6){
      int li = id; int t = (c >= 80); int cc = c - t*80;
      if (cc < 70 && k < 70) val = Wm_plain[((li*2+t)*70 + k)*70 + cc];
    } else if (id < 12){
      int li = id-6;
      int kk = (k < 70) ? k : ((k >= 80 && k < 150) ? 70 + (k-80) : -1);
      if (c < 70 && kk >= 0) val = Wu_plain[(li*140 + kk)*70 + c];
    } else if (id < 14){
      int blk = id-12; int t = (c >= 160); int cc = c - t*160;
      int kk = (k < 70) ? k : ((k >= 80 && k < 150) ? 70 + (k-80) : -1);
      if (cc < 140 && kk >= 0) val = Wm_ar[(((blk*2+t)*140) + kk)*140 + cc];
    } else if (id < 16){
      int blk = id-14;
      int kk = (k < 70) ? k : ((k >= 80 && k < 150) ? 70 + (k-80)
               : ((k >= 160 && k < 300) ? 140 + (k-160) : -1));
      if (c < 70 && kk >= 0) val = Wu_ar[(blk*280 + kk)*70 + c];
    } else {
      int typ = id-16;
      const float* Wi = typ ? Wi_mem : Wi_map;
      const float* Wh = typ ? Wh_mem : Wh_map;
      if (c < 192) val = (k < 64) ? Wi[c*64 + k] : Wh[c*64 + (k-64)];
      else { int cc = c-192; val = (k >= 64) ? Wh[(128+cc)*64 + (k-64)] : 0.f; }
    }
    BtArena[off + g] = f2bf(val);
  }
}

// bias arena (fp32): [0..960) plain msg [160]x6; [960..1440) plain upd [80]x6;
// [1440..2080) ar msg [320]x2; [2080..2240) ar upd [80]x2; [2240..2752) gru [256]x2
__global__ void k_prepBias(const float* __restrict__ bm_plain, const float* __restrict__ bu_plain,
                           const float* __restrict__ bm_ar, const float* __restrict__ bu_ar,
                           const float* __restrict__ bi_map, const float* __restrict__ bh_map,
                           const float* __restrict__ bi_mem, const float* __restrict__ bh_mem,
                           float* __restrict__ biasA){
  for (int g = threadIdx.x; g < 2752; g += 256){
    float val = 0.f;
    if (g < 960){ int li=g/160, c=g%160; int t=(c>=80); int cc=c-t*80;
      if (cc<70) val = bm_plain[(li*2+t)*70 + cc]; }
    else if (g < 1440){ int u=g-960; int li=u/80, c=u%80; if (c<70) val = bu_plain[li*70+c]; }
    else if (g < 2080){ int u=g-1440; int blk=u/320, c=u%320; int t=(c>=160); int cc=c-t*160;
      if (cc<140) val = bm_ar[(blk*2+t)*140 + cc]; }
    else if (g < 2240){ int u=g-2080; int blk=u/80, c=u%80; if (c<70) val = bu_ar[blk*70+c]; }
    else { int u=g-2240; int typ=u/256, c=u%256;
      const float* bi = typ ? bi_mem : bi_map; const float* bh = typ ? bh_mem : bh_map;
      val = (c < 192) ? (bi[c]+bh[c]) : bh[128 + (c-192)]; }
    biasA[g] = val;
  }
}

// ---------------- embed -> bf16 table (1.28 MB, L2-resident for the gather) ----------
__global__ void k_prepEmb(const float* __restrict__ embed, unsigned short* __restrict__ embB,
                          int total){
  int g = blockIdx.x*256 + threadIdx.x;
  if (g < total) embB[g] = f2bf(embed[g]);
}

// ---------------- init h = [one_hot(type,6) | zeros] bf16, stride 80 ----------------
__global__ void k_init_h(const int* __restrict__ type_idx, unsigned short* __restrict__ h, int N){
  int g = blockIdx.x*256 + threadIdx.x;
  if (g >= N*80) return;
  int n = g / 80, c = g - n*80;
  h[g] = (c < 6 && type_idx[n] == c) ? (unsigned short)0x3F80 : (unsigned short)0;
}

__global__ void k_compact(const int* __restrict__ type_idx, int* __restrict__ idxcat,
                          int* __restrict__ cnt, int N){
  int n = blockIdx.x*256 + threadIdx.x;
  if (n >= N) return;
  int t = type_idx[n];
  if (t == 0){ int p = atomicAdd(&cnt[0],1); if (p < CAPT) idxcat[p] = n; }
  else if (t == 5){ int p = atomicAdd(&cnt[1],1); if (p < CAPT) idxcat[CAPT+p] = n; }
}

// ---------------- CSR build, per-node edge count padded to multiple of 4 -------------
__global__ void k_count(const int* __restrict__ edst, int* __restrict__ deg, int TE){
  int i = blockIdx.x*256 + threadIdx.x;
  if (i < TE) atomicAdd(&deg[edst[i]], 1);
}
__global__ void k_scan1(const int* __restrict__ deg, int* __restrict__ off,
                        int* __restrict__ bsum, int N){
  __shared__ int sh[256];
  int t = threadIdx.x; int base = blockIdx.x*2048;
  int v[8]; int s = 0;
  for (int i=0;i<8;i++){
    int g = base + t*8 + i;
    int x = (g<N)? (((deg[g]+3)>>2)<<2) : 0;     // pad to x4
    v[i]=x; s+=x;
  }
  sh[t]=s; __syncthreads();
  for (int o=1;o<256;o<<=1){ int x = (t>=o)? sh[t-o]:0; __syncthreads(); sh[t]+=x; __syncthreads(); }
  if (t==255) bsum[blockIdx.x] = sh[255];
  int run = sh[t]-s;
  for (int i=0;i<8;i++){ int g = base + t*8 + i; if (g<N) off[g]=run; run+=v[i]; }
}
__global__ void k_scan2(int* bsum, int nb){
  if (threadIdx.x==0 && blockIdx.x==0){
    int run=0;
    for(int b=0;b<nb;b++){ int x=bsum[b]; bsum[b]=run; run+=x; }
    bsum[nb]=run;                                 // grand total (padded)
  }
}
__global__ void k_scan3(int* __restrict__ off, const int* __restrict__ bsum, int N, int nb){
  int g = blockIdx.x*256+threadIdx.x;
  if (g < N) off[g] += bsum[g>>11];
  if (g == 0) off[N] = bsum[nb];
}
__global__ void k_fill(const int* __restrict__ esrc, const int* __restrict__ edst,
                       const int* __restrict__ off, int* __restrict__ cur,
                       int* __restrict__ edata, int TE, int E){
  int i = blockIdx.x*256 + threadIdx.x;
  if (i >= TE) return;
  int d = edst[i];
  int pos = off[d] + atomicAdd(&cur[d], 1);
  edata[pos] = (esrc[i] << 1) | (i >= E ? 1 : 0);
}
// pad slots [deg, deg4) with a duplicate of the node's first edge (idempotent for max)
__global__ void k_pad(const int* __restrict__ off, const int* __restrict__ cur,
                      int* __restrict__ edata, int N){
  int n = blockIdx.x*256 + threadIdx.x;
  if (n >= N) return;
  int d = cur[n];
  if (d == 0) return;
  int d4 = ((d+3)>>2)<<2;
  int base = off[n];
  int first = edata[base];
  for (int i = d; i < d4; i++) edata[base+i] = first;
}

// ======== kgru v3: persistent GRU — 32-row blocks (2x grid), dbuf, 1 barrier/step ====
__global__ __launch_bounds__(256) void kgru(
    const int* __restrict__ idxcat, const int* __restrict__ tokens,
    const unsigned short* __restrict__ embB,
    const unsigned short* __restrict__ Bt, const unsigned short* __restrict__ Bt2,
    const float* __restrict__ bias, const float* __restrict__ bias2,
    unsigned short* __restrict__ hOut)
{
  __shared__ __align__(16) unsigned short As[2][GRR*GLD];
  __shared__ int tokS[GRR*8];
  __shared__ int idxS[GRR];
  int rb = blockIdx.y * CAPT + blockIdx.x * GRR;
  if (idxcat[rb] < 0) return;                      // all-pad block
  int t = threadIdx.x;
  int lane = t & 63, m = lane & 15, q = lane >> 4, w = t >> 6;
  const unsigned short* Bsel = blockIdx.y ? Bt2 : Bt;
  const float* bsel = blockIdx.y ? bias2 : bias;
  short8 breg[4][4]; float bv[4];
  #pragma unroll
  for (int j=0;j<4;j++){
    int col = (w + 4*j)*16 + m;
    bv[j] = bsel[col];
    #pragma unroll
    for (int kt=0;kt<4;kt++)
      breg[j][kt] = *(const short8*)&Bsel[(size_t)col*128 + kt*32 + q*8];
  }
  if (t < GRR) idxS[t] = idxcat[rb + t];
  if (t < GRR*8){
    int nd = idxcat[rb + (t>>3)]; if (nd < 0) nd = 0;
    tokS[t] = tokens[nd*8 + (t & 7)];
  }
  __syncthreads();                                 // tokS ready
  // stage X(0) + zero H(0) into buf 0
  if (t < GRR*8){
    int row = t >> 3, ch = t & 7;
    *(uint4*)&As[0][row*GLD + ch*8] = *(const uint4*)&embB[(size_t)tokS[row*8]*64 + ch*8];
  }
  for (int j = t; j < GRR*32; j += 256){
    int row = j >> 5, k2 = (j & 31)*2;
    *(unsigned int*)&As[0][row*GLD + 64 + k2] = 0;
  }
  __syncthreads();
  unsigned short hreg[2][4];
  #pragma unroll
  for (int rt=0;rt<2;rt++)
    #pragma unroll
    for (int i=0;i<4;i++) hreg[rt][i] = 0;
  int u = w*16 + m;
  int p = 0;
  for (int s = 0; s < 8; s++){
    uint4 xr;
    if (s < 7 && t < GRR*8){                       // prefetch X(s+1) early (global)
      int row = t >> 3, ch = t & 7;
      xr = *(const uint4*)&embB[(size_t)tokS[row*8 + s + 1]*64 + ch*8];
    }
    f32x4 acc[2][4] = {};
    #pragma unroll
    for (int kt=0;kt<4;kt++){
      short8 af[2];
      #pragma unroll
      for (int rt=0;rt<2;rt++)
        af[rt] = *(const short8*)&As[p][(rt*16+m)*GLD + kt*32 + q*8];
      #pragma unroll
      for (int j=0;j<4;j++)
        #pragma unroll
        for (int rt=0;rt<2;rt++)
          acc[rt][j] = __builtin_amdgcn_mfma_f32_16x16x32_bf16(af[rt], breg[j][kt], acc[rt][j], 0,0,0);
    }
    #pragma unroll
    for (int rt=0;rt<2;rt++){
      #pragma unroll
      for (int i=0;i<4;i++){
        float rr = fsig_(acc[rt][0][i] + bv[0]);
        float zz = fsig_(acc[rt][1][i] + bv[1]);
        float hn = acc[rt][3][i] + bv[3];
        float nn = ftanh_(acc[rt][2][i] + bv[2] + (rr - 1.f)*hn);
        float hp = bf2f(hreg[rt][i]);
        hreg[rt][i] = f2bf((1.f - zz)*nn + zz*hp);
      }
    }
    if (s < 7){
      #pragma unroll
      for (int rt=0;rt<2;rt++)
        #pragma unroll
        for (int i=0;i<4;i++)
          As[p^1][(rt*16 + q*4 + i)*GLD + 64 + u] = hreg[rt][i];
      if (t < GRR*8){
        int row = t >> 3, ch = t & 7;
        *(uint4*)&As[p^1][row*GLD + ch*8] = xr;
      }
      __syncthreads();
      p ^= 1;
    } else {
      #pragma unroll
      for (int rt=0;rt<2;rt++)
        #pragma unroll
        for (int i=0;i<4;i++){
          int nd = idxS[rt*16 + q*4 + i];
          if (nd >= 0) hOut[(size_t)nd*80 + 6 + u] = hreg[rt][i];
        }
    }
  }
}

// ======== wgemm: B-in-registers MFMA GEMM, up to 3 concatenated A segments =========
template<int RTR, int KT, int CT>
__global__ __launch_bounds__(256) void wgemm(
    const unsigned short* __restrict__ A0, int w0, int ldA0,
    const unsigned short* __restrict__ A1, int w1, int ldA1,
    const unsigned short* __restrict__ A2, int w2, int ldA2,
    const unsigned short* __restrict__ Bt, int KpB,
    const float* __restrict__ bias,
    unsigned short* __restrict__ C, int ldC,
    int rows, int tiles, int act)
{
  constexpr int Kpad = KT*32;
  constexpr int LD   = Kpad + 8;
  constexpr int NRT  = RTR/16;
  constexpr int CPT  = (RTR*Kpad/8)/256;
  __shared__ __align__(16) unsigned short As[2][RTR*LD];
  int t = threadIdx.x;
  int lane = t & 63, m = lane & 15, q = lane >> 4, w = t >> 6;
  int tileBase = blockIdx.y * (4*CT);
  int rtEnd = (rows + RTR - 1)/RTR;
  int tr = blockIdx.x;
  if (tr >= rtEnd) return;

  short8 breg[CT][KT]; float bv[CT]; bool val[CT]; int colr[CT];
  #pragma unroll
  for (int j=0;j<CT;j++){
    int tt = tileBase + w + 4*j;
    val[j] = (tt < tiles);
    int col = tt*16 + m;
    colr[j] = col;
    bv[j] = 0.f;
    if (val[j]){
      bv[j] = bias[col];
      #pragma unroll
      for (int kt=0;kt<KT;kt++)
        breg[j][kt] = *(const short8*)&Bt[(size_t)col*KpB + kt*32 + q*8];
    } else {
      #pragma unroll
      for (int kt=0;kt<KT;kt++) breg[j][kt] = (short8){0,0,0,0,0,0,0,0};
    }
  }

  int w01 = w0 + w1, w012 = w0 + w1 + w2;
  uint4 r[CPT];
  auto loadRegs = [&](int trr){
    #pragma unroll
    for (int i=0;i<CPT;i++){
      int c = i*256 + t;
      int row = c / (KT*4), kc = (c - row*(KT*4))*8;
      int gr = trr*RTR + row;
      uint4 v = {0,0,0,0};
      if (gr < rows && kc < w012){
        const unsigned short* sp;
        if (kc < w0)       sp = A0 + (size_t)gr*ldA0 + kc;
        else if (kc < w01) sp = A1 + (size_t)gr*ldA1 + (kc - w0);
        else               sp = A2 + (size_t)gr*ldA2 + (kc - w01);
        v = *(const uint4*)sp;
      }
      r[i] = v;
    }
  };
  auto dsw = [&](int p){
    #pragma unroll
    for (int i=0;i<CPT;i++){
      int c = i*256 + t;
      int row = c / (KT*4), kc = (c - row*(KT*4))*8;
      *(uint4*)&As[p][row*LD + kc] = r[i];
    }
  };

  loadRegs(tr);
  dsw(0);
  int p = 0;
  for (;;){
    int nxt = tr + gridDim.x;
    bool hasNext = (nxt < rtEnd);
    if (hasNext) loadRegs(nxt);
    __syncthreads();
    f32x4 acc[NRT][CT] = {};
    #pragma unroll
    for (int kt=0;kt<KT;kt++){
      short8 af[NRT];
      #pragma unroll
      for (int rt=0;rt<NRT;rt++)
        af[rt] = *(const short8*)&As[p][(rt*16+m)*LD + kt*32 + q*8];
      #pragma unroll
      for (int j=0;j<CT;j++)
        #pragma unroll
        for (int rt=0;rt<NRT;rt++)
          acc[rt][j] = __builtin_amdgcn_mfma_f32_16x16x32_bf16(af[rt], breg[j][kt], acc[rt][j], 0,0,0);
    }
    bool tfull = (tr*RTR + RTR <= rows);
#define EPILOG(CHK)                                                         \
    _Pragma("unroll")                                                       \
    for (int rt=0;rt<NRT;rt++){                                             \
      int rbase = tr*RTR + rt*16 + q*4;                                     \
      _Pragma("unroll")                                                     \
      for (int j=0;j<CT;j++){                                               \
        if (!val[j]) continue;                                              \
        _Pragma("unroll")                                                   \
        for (int i=0;i<4;i++){                                              \
          int grow = rbase + i;                                             \
          if (CHK && grow >= rows) continue;                                \
          float v = acc[rt][j][i] + bv[j];                                  \
          if (act == 1) v = fgelu_(v);                                      \
          else if (act == 2) v = ftanh_(v);                                 \
          C[(size_t)grow*ldC + colr[j]] = f2bf(v);                          \
        }                                                                   \
      }                                                                     \
    }
    if (tfull){ EPILOG(false) } else { EPILOG(true) }
#undef EPILOG
    if (!hasNext) break;
    dsw(p^1);
    p ^= 1; tr = nxt;
  }
}

// ---------------- CSR gather + segment max; scalarized + 2-deep pipelined ----------
// node wave-uniform (readfirstlane) -> edata via s_load, row bases on scalar pipe.
// Row loads for group i+1 are issued before group i's maxes consume their loads:
// ~8 row loads in flight per wave.
__global__ __launch_bounds__(256) void k_aggregate(
    const int* __restrict__ off, const int* __restrict__ edata,
    const unsigned short* __restrict__ P2, int ldP, int off1,
    unsigned short* __restrict__ agg, int M, int N, int WPN)
{
  int t = threadIdx.x;
  int lane = t & 63, w = t >> 6;
  int node, c;
  if (WPN == 1){
    node = blockIdx.x*4 + w;
    c = 2*lane;
  } else {
    node = blockIdx.x*2 + (w >> 1);
    c = (w & 1)*80 + 2*lane;
  }
  node = __builtin_amdgcn_readfirstlane(node);   // wave-uniform in truth; force SGPR
  if (node >= N) return;
  bool act = (lane < 40);
  int e0 = __builtin_amdgcn_readfirstlane(off[node]);
  int e1 = __builtin_amdgcn_readfirstlane(off[node+1]);
  const float NEG = -__builtin_inff();
  float f0 = NEG, f1 = NEG;
  if (e0 < e1){
    int4 cur = *(const int4*)&edata[e0];
    unsigned int r0=0, r1=0, r2=0, r3=0;
    {
      int b0 = (cur.x>>1)*ldP + (cur.x&1)*off1;
      int b1 = (cur.y>>1)*ldP + (cur.y&1)*off1;
      int b2 = (cur.z>>1)*ldP + (cur.z&1)*off1;
      int b3 = (cur.w>>1)*ldP + (cur.w&1)*off1;
      if (act){
        r0 = *(const unsigned int*)(P2 + b0 + c);
        r1 = *(const unsigned int*)(P2 + b1 + c);
        r2 = *(const unsigned int*)(P2 + b2 + c);
        r3 = *(const unsigned int*)(P2 + b3 + c);
      }
    }
    for (int e = e0;;){
      int en = e + 4;
      bool has = en < e1;
      unsigned int n0=0, n1=0, n2=0, n3=0;
      if (has){
        int4 nx = *(const int4*)&edata[en];      // scalar prefetch of next group
        int b0 = (nx.x>>1)*ldP + (nx.x&1)*off1;
        int b1 = (nx.y>>1)*ldP + (nx.y&1)*off1;
        int b2 = (nx.z>>1)*ldP + (nx.z&1)*off1;
        int b3 = (nx.w>>1)*ldP + (nx.w&1)*off1;
        if (act){
          n0 = *(const unsigned int*)(P2 + b0 + c);   // issue next rows before
          n1 = *(const unsigned int*)(P2 + b1 + c);   // consuming current
          n2 = *(const unsigned int*)(P2 + b2 + c);
          n3 = *(const unsigned int*)(P2 + b3 + c);
        }
      }
      if (act){
        f0 = fmaxf(f0, fmaxf(fmaxf(__uint_as_float(r0<<16), __uint_as_float(r1<<16)),
                             fmaxf(__uint_as_float(r2<<16), __uint_as_float(r3<<16))));
        f1 = fmaxf(f1, fmaxf(fmaxf(__uint_as_float(r0&0xFFFF0000u), __uint_as_float(r1&0xFFFF0000u)),
                             fmaxf(__uint_as_float(r2&0xFFFF0000u), __uint_as_float(r3&0xFFFF0000u))));
      }
      if (!has) break;
      r0 = n0; r1 = n1; r2 = n2; r3 = n3;
      e = en;
    }
  }
  if (act){
    unsigned int o = (__float_as_uint(f0 == NEG ? 0.f : f0) >> 16)
                   |  (__float_as_uint(f1 == NEG ? 0.f : f1) & 0xFFFF0000u);
    *(unsigned int*)(agg + (size_t)node*M + c) = o;
  }
}

// ---------------- final head ----------------
__global__ void k_head(const unsigned short* __restrict__ h, const int* __restrict__ entry,
                       const float* __restrict__ W1, const float* __restrict__ b1,
                       const float* __restrict__ W2, const float* __restrict__ b2,
                       float* __restrict__ out){
  __shared__ float x[70], x1[70];
  int t = threadIdx.x;
  if (t < 70) x[t] = bf2f(h[(size_t)(*entry)*80 + t]);
  __syncthreads();
  if (t < 70){
    float s = b1[t];
    for (int i=0;i<70;i++) s += x[i]*W1[i*70 + t];
    x1[t] = fmaxf(s, 0.f);
  }
  __syncthreads();
  if (t < 640){
    float s = b2[t];
    for (int i=0;i<70;i++) s += x1[i]*W2[i*640 + t];
    out[t] = s;
  }
}

extern "C" void kernel_launch(void* const* d_in, const int* in_sizes, int n_in,
                              void* d_out, int out_size, void* d_ws, size_t ws_size,
                              hipStream_t stream) {
  const int*   tokens   = (const int*)d_in[0];
  const int*   type_idx = (const int*)d_in[1];
  const int*   esrc     = (const int*)d_in[2];
  const int*   edst     = (const int*)d_in[3];
  const int*   entry    = (const int*)d_in[4];
  const float* embed    = (const float*)d_in[5];
  const float* Wi_map   = (const float*)d_in[6];
  const float* Wh_map   = (const float*)d_in[7];
  const float* bi_map   = (const float*)d_in[8];
  const float* bh_map   = (const float*)d_in[9];
  const float* Wi_mem   = (const float*)d_in[10];
  const float* Wh_mem   = (const float*)d_in[11];
  const float* bi_mem   = (const float*)d_in[12];
  const float* bh_mem   = (const float*)d_in[13];
  const float* Wm_plain = (const float*)d_in[14];
  const float* bm_plain = (const float*)d_in[15];
  const float* Wu_plain = (const float*)d_in[16];
  const float* bu_plain = (const float*)d_in[17];
  const float* Wm_ar    = (const float*)d_in[18];
  const float* bm_ar    = (const float*)d_in[19];
  const float* Wu_ar    = (const float*)d_in[20];
  const float* bu_ar    = (const float*)d_in[21];
  const float* W1 = (const float*)d_in[22];
  const float* b1 = (const float*)d_in[23];
  const float* W2 = (const float*)d_in[24];
  const float* b2 = (const float*)d_in[25];
  float* out = (float*)d_out;

  const int N  = in_sizes[1];      // 100000
  const int TE = in_sizes[2];      // 500000
  const int E  = TE / 2;
  const int V64 = in_sizes[5];     // V*DE = 640000

  char* p = (char*)d_ws;
  auto alloc = [&](size_t bytes)->char* { char* r = p; p += (bytes + 255) & ~(size_t)255; return r; };
  unsigned short* hA  = (unsigned short*)alloc((size_t)N*80*2);
  unsigned short* hB  = (unsigned short*)alloc((size_t)N*80*2);
  unsigned short* hC  = (unsigned short*)alloc((size_t)N*80*2);
  unsigned short* P2  = (unsigned short*)alloc((size_t)N*320*2);
  unsigned short* agg = (unsigned short*)alloc((size_t)N*160*2);
  int* deg    = (int*)alloc((size_t)N*4);
  int* curp   = (int*)alloc((size_t)N*4);
  int* off    = (int*)alloc((size_t)(N+8)*4);
  int* edata  = (int*)alloc((size_t)(TE + 4*N + 16)*4);            // padded CSR
  int* sbsum  = (int*)alloc(256*4);
  int* cnt    = (int*)alloc(16*4);
  int* idxcat = (int*)alloc((size_t)R2*4);
  unsigned short* BtA  = (unsigned short*)alloc(388096*2);
  float* biasA = (float*)alloc(2752*4);
  unsigned short* embB = (unsigned short*)alloc((size_t)V64*2);

  hipMemsetAsync(idxcat, 0xFF, (size_t)R2*4, stream);
  hipMemsetAsync(cnt,    0,    16*4, stream);
  hipMemsetAsync(deg,    0,    (size_t)N*4, stream);
  hipMemsetAsync(curp,   0,    (size_t)N*4, stream);

  k_prepB<<<dim3(8,18), 256, 0, stream>>>(Wm_plain, Wu_plain, Wm_ar, Wu_ar,
                                          Wi_map, Wh_map, Wi_mem, Wh_mem, BtA);
  k_prepBias<<<1, 256, 0, stream>>>(bm_plain, bu_plain, bm_ar, bu_ar,
                                    bi_map, bh_map, bi_mem, bh_mem, biasA);
  k_prepEmb<<<(V64+255)/256, 256, 0, stream>>>(embed, embB, V64);
  k_init_h<<<(N*80+255)/256, 256, 0, stream>>>(type_idx, hA, N);
  k_compact<<<(N+255)/256, 256, 0, stream>>>(type_idx, idxcat, cnt, N);

  k_count<<<(TE+255)/256, 256, 0, stream>>>(edst, deg, TE);
  int nb = (N + 2047)/2048;
  k_scan1<<<nb, 256, 0, stream>>>(deg, off, sbsum, N);
  k_scan2<<<1, 64, 0, stream>>>(sbsum, nb);
  k_scan3<<<(N+255)/256, 256, 0, stream>>>(off, sbsum, N, nb);
  k_fill<<<(TE+255)/256, 256, 0, stream>>>(esrc, edst, off, curp, edata, TE, E);
  k_pad<<<(N+255)/256, 256, 0, stream>>>(off, curp, edata, N);

  // ---- GRU: one persistent launch (8 steps internal), gather+scatter fused ----
  kgru<<<dim3(CAPT/GRR, 2), 256, 0, stream>>>(
      idxcat, tokens, embB,
      BtA + 322560, BtA + 322560 + 32768,
      biasA + 2240, biasA + 2240 + 256, hA);

  // ---- 2 blocks x (3 plain MP + concat-residual AR MP) ----
  unsigned short* cur = hA; unsigned short* f1 = hB; unsigned short* f2 = hC;
  int li = 0;
  for (int blk = 0; blk < 2; blk++){
    unsigned short* saved = cur;
    unsigned short* ins[3]  = {cur, f1, f2};
    unsigned short* outs[3] = {f1, f2, f1};
    for (int j = 0; j < 3; j++){
      unsigned short* X = ins[j]; unsigned short* Yo = outs[j];
      // msg: [N,80] @ [96->160] (both edge types fused in cols)
      wgemm<64,3,3><<<dim3(1024,1), 256, 0, stream>>>(
          X, 80, 80,  nullptr, 0, 0,  nullptr, 0, 0,
          BtA + li*15360, 96, biasA + li*160,
          P2, 160, N, 10, 0);
      k_aggregate<<<(N+3)/4, 256, 0, stream>>>(off, edata, P2, 160, 80, agg, 80, N, 1);
      // upd: [N,80|80] @ [160->80]
      wgemm<64,5,2><<<dim3(1024,1), 256, 0, stream>>>(
          X, 80, 80,  agg, 80, 80,  nullptr, 0, 0,
          BtA + 92160 + li*12800, 160, biasA + 960 + li*80,
          Yo, 80, N, 5, 0);
      li++;
    }
    // AR msg: [N,80|80] @ [160->320], gelu; y splits 20 col tiles into 12+8
    wgemm<64,5,3><<<dim3(512,2), 256, 0, stream>>>(
        saved, 80, 80,  f1, 80, 80,  nullptr, 0, 0,
        BtA + 168960 + blk*51200, 160, biasA + 1440 + blk*320,
        P2, 320, N, 20, 1 /*gelu*/);
    k_aggregate<<<(N+1)/2, 256, 0, stream>>>(off, edata, P2, 320, 160, agg, 160, N, 2);
    // AR upd: [N,80|80|160] @ [320->80], tanh; 32-row tiles (K=320 LDS)
    wgemm<32,10,2><<<dim3(1024,1), 256, 0, stream>>>(
        saved, 80, 80,  f1, 80, 80,  agg, 160, 160,
        BtA + 271360 + blk*25600, 320, biasA + 2080 + blk*80,
        f2, 80, N, 5, 2 /*tanh*/);
    unsigned short* t3 = cur; cur = f2; f2 = t3;
  }

  k_head<<<1, 640, 0, stream>>>(cur, entry, W1, b1, W2, b2, out);
}

// Round 12
// 933.214 us; speedup vs baseline: 1.0194x; 1.0194x over previous
//
#include <hip/hip_runtime.h>
#include <math.h>

#define CAPT 20480              // per-type compacted-node capacity (actual ~16.7k)
#define R2   (2*CAPT)
#define GLD  136                // kgru LDS row stride (ushorts): breaks pow2 banking
#define GRR  32                 // kgru rows per block

typedef __attribute__((ext_vector_type(8))) short short8;
typedef __attribute__((ext_vector_type(4))) float f32x4;

// ---- fast transcendentals: v_exp_f32 / v_rcp_f32 based; err ~1e-7 << bf16 ulp ----
__device__ __forceinline__ float fexp2_(float x){ return __builtin_amdgcn_exp2f(x); }
__device__ __forceinline__ float frcp_(float x){ return __builtin_amdgcn_rcpf(x); }
__device__ __forceinline__ float ftanh_(float x){
  float ax = __builtin_fabsf(x);
  float t = fexp2_(-2.885390082f * ax);          // e^{-2|x|}
  float r = (1.f - t) * frcp_(1.f + t);
  return __builtin_copysignf(r, x);
}
__device__ __forceinline__ float fsig_(float x){
  return frcp_(1.f + fexp2_(-1.442695041f * x));
}
__device__ __forceinline__ float fgelu_(float x){
  const float c = 0.7978845608028654f;
  return 0.5f*x*(1.f + ftanh_(c*(x + 0.044715f*x*x*x)));
}
__device__ __forceinline__ unsigned short f2bf(float x){
  unsigned int u = __float_as_uint(x);
  return (unsigned short)((u + 0x7FFFu + ((u>>16)&1u)) >> 16);
}
__device__ __forceinline__ float bf2f(unsigned short v){
  return __uint_as_float(((unsigned int)v) << 16);
}

// ---------------- weight prep: transposed bf16 B arena, padded to 16-mult segments ----
// Arena layout (bf16 elems):
//  [0..6)      plain msg li:  [160][96]   off = li*15360
//  [6..12)     plain upd li:  [80][160]   off = 92160 + li*12800
//  [12..14)    ar msg blk:    [320][160]  off = 168960 + blk*51200
//  [14..16)    ar upd blk:    [80][320]   off = 271360 + blk*25600
//  [16..18)    gru typ:       [256][128]  off = 322560 + typ*32768
__global__ void k_prepB(const float* __restrict__ Wm_plain, const float* __restrict__ Wu_plain,
                        const float* __restrict__ Wm_ar, const float* __restrict__ Wu_ar,
                        const float* __restrict__ Wi_map, const float* __restrict__ Wh_map,
                        const float* __restrict__ Wi_mem, const float* __restrict__ Wh_mem,
                        unsigned short* __restrict__ BtArena){
  int id = blockIdx.y;
  int Kp, elems, off;
  if (id < 6){ Kp=96;  elems=15360; off=id*15360; }
  else if (id < 12){ Kp=160; elems=12800; off=92160+(id-6)*12800; }
  else if (id < 14){ Kp=160; elems=51200; off=168960+(id-12)*51200; }
  else if (id < 16){ Kp=320; elems=25600; off=271360+(id-14)*25600; }
  else { Kp=128; elems=32768; off=322560+(id-16)*32768; }
  for (int g = blockIdx.x*256 + threadIdx.x; g < elems; g += 8*256){
    int c = g / Kp, k = g - c*Kp;
    float val = 0.f;
    if (id < 6){
      int li = id; int t = (c >= 80); int cc = c - t*80;
      if (cc < 70 && k < 70) val = Wm_plain[((li*2+t)*70 + k)*70 + cc];
    } else if (id < 12){
      int li = id-6;
      int kk = (k < 70) ? k : ((k >= 80 && k < 150) ? 70 + (k-80) : -1);
      if (c < 70 && kk >= 0) val = Wu_plain[(li*140 + kk)*70 + c];
    } else if (id < 14){
      int blk = id-12; int t = (c >= 160); int cc = c - t*160;
      int kk = (k < 70) ? k : ((k >= 80 && k < 150) ? 70 + (k-80) : -1);
      if (cc < 140 && kk >= 0) val = Wm_ar[(((blk*2+t)*140) + kk)*140 + cc];
    } else if (id < 16){
      int blk = id-14;
      int kk = (k < 70) ? k : ((k >= 80 && k < 150) ? 70 + (k-80)
               : ((k >= 160 && k < 300) ? 140 + (k-160) : -1));
      if (c < 70 && kk >= 0) val = Wu_ar[(blk*280 + kk)*70 + c];
    } else {
      int typ = id-16;
      const float* Wi = typ ? Wi_mem : Wi_map;
      const float* Wh = typ ? Wh_mem : Wh_map;
      if (c < 192) val = (k < 64) ? Wi[c*64 + k] : Wh[c*64 + (k-64)];
      else { int cc = c-192; val = (k >= 64) ? Wh[(128+cc)*64 + (k-64)] : 0.f; }
    }
    BtArena[off + g] = f2bf(val);
  }
}

// bias arena (fp32): [0..960) plain msg [160]x6; [960..1440) plain upd [80]x6;
// [1440..2080) ar msg [320]x2; [2080..2240) ar upd [80]x2; [2240..2752) gru [256]x2
__global__ void k_prepBias(const float* __restrict__ bm_plain, const float* __restrict__ bu_plain,
                           const float* __restrict__ bm_ar, const float* __restrict__ bu_ar,
                           const float* __restrict__ bi_map, const float* __restrict__ bh_map,
                           const float* __restrict__ bi_mem, const float* __restrict__ bh_mem,
                           float* __restrict__ biasA){
  for (int g = threadIdx.x; g < 2752; g += 256){
    float val = 0.f;
    if (g < 960){ int li=g/160, c=g%160; int t=(c>=80); int cc=c-t*80;
      if (cc<70) val = bm_plain[(li*2+t)*70 + cc]; }
    else if (g < 1440){ int u=g-960; int li=u/80, c=u%80; if (c<70) val = bu_plain[li*70+c]; }
    else if (g < 2080){ int u=g-1440; int blk=u/320, c=u%320; int t=(c>=160); int cc=c-t*160;
      if (cc<140) val = bm_ar[(blk*2+t)*140 + cc]; }
    else if (g < 2240){ int u=g-2080; int blk=u/80, c=u%80; if (c<70) val = bu_ar[blk*70+c]; }
    else { int u=g-2240; int typ=u/256, c=u%256;
      const float* bi = typ ? bi_mem : bi_map; const float* bh = typ ? bh_mem : bh_map;
      val = (c < 192) ? (bi[c]+bh[c]) : bh[128 + (c-192)]; }
    biasA[g] = val;
  }
}

// ---------------- embed -> bf16 table (1.28 MB, L2-resident for the gather) ----------
__global__ void k_prepEmb(const float* __restrict__ embed, unsigned short* __restrict__ embB,
                          int total){
  int g = blockIdx.x*256 + threadIdx.x;
  if (g < total) embB[g] = f2bf(embed[g]);
}

// ---------------- init h = [one_hot(type,6) | zeros] bf16, stride 80 ----------------
__global__ void k_init_h(const int* __restrict__ type_idx, unsigned short* __restrict__ h, int N){
  int g = blockIdx.x*256 + threadIdx.x;
  if (g >= N*80) return;
  int n = g / 80, c = g - n*80;
  h[g] = (c < 6 && type_idx[n] == c) ? (unsigned short)0x3F80 : (unsigned short)0;
}

__global__ void k_compact(const int* __restrict__ type_idx, int* __restrict__ idxcat,
                          int* __restrict__ cnt, int N){
  int n = blockIdx.x*256 + threadIdx.x;
  if (n >= N) return;
  int t = type_idx[n];
  if (t == 0){ int p = atomicAdd(&cnt[0],1); if (p < CAPT) idxcat[p] = n; }
  else if (t == 5){ int p = atomicAdd(&cnt[1],1); if (p < CAPT) idxcat[CAPT+p] = n; }
}

// ---------------- CSR build, per-node edge count padded to multiple of 4 -------------
__global__ void k_count(const int* __restrict__ edst, int* __restrict__ deg, int TE){
  int i = blockIdx.x*256 + threadIdx.x;
  if (i < TE) atomicAdd(&deg[edst[i]], 1);
}
__global__ void k_scan1(const int* __restrict__ deg, int* __restrict__ off,
                        int* __restrict__ bsum, int N){
  __shared__ int sh[256];
  int t = threadIdx.x; int base = blockIdx.x*2048;
  int v[8]; int s = 0;
  for (int i=0;i<8;i++){
    int g = base + t*8 + i;
    int x = (g<N)? (((deg[g]+3)>>2)<<2) : 0;     // pad to x4
    v[i]=x; s+=x;
  }
  sh[t]=s; __syncthreads();
  for (int o=1;o<256;o<<=1){ int x = (t>=o)? sh[t-o]:0; __syncthreads(); sh[t]+=x; __syncthreads(); }
  if (t==255) bsum[blockIdx.x] = sh[255];
  int run = sh[t]-s;
  for (int i=0;i<8;i++){ int g = base + t*8 + i; if (g<N) off[g]=run; run+=v[i]; }
}
__global__ void k_scan2(int* bsum, int nb){
  if (threadIdx.x==0 && blockIdx.x==0){
    int run=0;
    for(int b=0;b<nb;b++){ int x=bsum[b]; bsum[b]=run; run+=x; }
    bsum[nb]=run;                                 // grand total (padded)
  }
}
__global__ void k_scan3(int* __restrict__ off, const int* __restrict__ bsum, int N, int nb){
  int g = blockIdx.x*256+threadIdx.x;
  if (g < N) off[g] += bsum[g>>11];
  if (g == 0) off[N] = bsum[nb];
}
__global__ void k_fill(const int* __restrict__ esrc, const int* __restrict__ edst,
                       const int* __restrict__ off, int* __restrict__ cur,
                       int* __restrict__ edata, int TE, int E){
  int i = blockIdx.x*256 + threadIdx.x;
  if (i >= TE) return;
  int d = edst[i];
  int pos = off[d] + atomicAdd(&cur[d], 1);
  edata[pos] = (esrc[i] << 1) | (i >= E ? 1 : 0);
}
// pad slots [deg, deg4) with a duplicate of the node's first edge (idempotent for max)
__global__ void k_pad(const int* __restrict__ off, const int* __restrict__ cur,
                      int* __restrict__ edata, int N){
  int n = blockIdx.x*256 + threadIdx.x;
  if (n >= N) return;
  int d = cur[n];
  if (d == 0) return;
  int d4 = ((d+3)>>2)<<2;
  int base = off[n];
  int first = edata[base];
  for (int i = d; i < d4; i++) edata[base+i] = first;
}

// ======== kgru v3: persistent GRU — 32-row blocks, dbuf, 1 barrier/step ============
__global__ __launch_bounds__(256) void kgru(
    const int* __restrict__ idxcat, const int* __restrict__ tokens,
    const unsigned short* __restrict__ embB,
    const unsigned short* __restrict__ Bt, const unsigned short* __restrict__ Bt2,
    const float* __restrict__ bias, const float* __restrict__ bias2,
    unsigned short* __restrict__ hOut)
{
  __shared__ __align__(16) unsigned short As[2][GRR*GLD];
  __shared__ int tokS[GRR*8];
  __shared__ int idxS[GRR];
  int rb = blockIdx.y * CAPT + blockIdx.x * GRR;
  if (idxcat[rb] < 0) return;                      // all-pad block
  int t = threadIdx.x;
  int lane = t & 63, m = lane & 15, q = lane >> 4, w = t >> 6;
  const unsigned short* Bsel = blockIdx.y ? Bt2 : Bt;
  const float* bsel = blockIdx.y ? bias2 : bias;
  short8 breg[4][4]; float bv[4];
  #pragma unroll
  for (int j=0;j<4;j++){
    int col = (w + 4*j)*16 + m;
    bv[j] = bsel[col];
    #pragma unroll
    for (int kt=0;kt<4;kt++)
      breg[j][kt] = *(const short8*)&Bsel[(size_t)col*128 + kt*32 + q*8];
  }
  if (t < GRR) idxS[t] = idxcat[rb + t];
  if (t < GRR*8){
    int nd = idxcat[rb + (t>>3)]; if (nd < 0) nd = 0;
    tokS[t] = tokens[nd*8 + (t & 7)];
  }
  __syncthreads();                                 // tokS ready
  if (t < GRR*8){
    int row = t >> 3, ch = t & 7;
    *(uint4*)&As[0][row*GLD + ch*8] = *(const uint4*)&embB[(size_t)tokS[row*8]*64 + ch*8];
  }
  for (int j = t; j < GRR*32; j += 256){
    int row = j >> 5, k2 = (j & 31)*2;
    *(unsigned int*)&As[0][row*GLD + 64 + k2] = 0;
  }
  __syncthreads();
  unsigned short hreg[2][4];
  #pragma unroll
  for (int rt=0;rt<2;rt++)
    #pragma unroll
    for (int i=0;i<4;i++) hreg[rt][i] = 0;
  int u = w*16 + m;
  int p = 0;
  for (int s = 0; s < 8; s++){
    uint4 xr;
    if (s < 7 && t < GRR*8){                       // prefetch X(s+1) early (global)
      int row = t >> 3, ch = t & 7;
      xr = *(const uint4*)&embB[(size_t)tokS[row*8 + s + 1]*64 + ch*8];
    }
    f32x4 acc[2][4] = {};
    #pragma unroll
    for (int kt=0;kt<4;kt++){
      short8 af[2];
      #pragma unroll
      for (int rt=0;rt<2;rt++)
        af[rt] = *(const short8*)&As[p][(rt*16+m)*GLD + kt*32 + q*8];
      #pragma unroll
      for (int j=0;j<4;j++)
        #pragma unroll
        for (int rt=0;rt<2;rt++)
          acc[rt][j] = __builtin_amdgcn_mfma_f32_16x16x32_bf16(af[rt], breg[j][kt], acc[rt][j], 0,0,0);
    }
    #pragma unroll
    for (int rt=0;rt<2;rt++){
      #pragma unroll
      for (int i=0;i<4;i++){
        float rr = fsig_(acc[rt][0][i] + bv[0]);
        float zz = fsig_(acc[rt][1][i] + bv[1]);
        float hn = acc[rt][3][i] + bv[3];
        float nn = ftanh_(acc[rt][2][i] + bv[2] + (rr - 1.f)*hn);
        float hp = bf2f(hreg[rt][i]);
        hreg[rt][i] = f2bf((1.f - zz)*nn + zz*hp);
      }
    }
    if (s < 7){
      #pragma unroll
      for (int rt=0;rt<2;rt++)
        #pragma unroll
        for (int i=0;i<4;i++)
          As[p^1][(rt*16 + q*4 + i)*GLD + 64 + u] = hreg[rt][i];
      if (t < GRR*8){
        int row = t >> 3, ch = t & 7;
        *(uint4*)&As[p^1][row*GLD + ch*8] = xr;
      }
      __syncthreads();
      p ^= 1;
    } else {
      #pragma unroll
      for (int rt=0;rt<2;rt++)
        #pragma unroll
        for (int i=0;i<4;i++){
          int nd = idxS[rt*16 + q*4 + i];
          if (nd >= 0) hOut[(size_t)nd*80 + 6 + u] = hreg[rt][i];
        }
    }
  }
}

// ======== wgemm: B-in-registers MFMA GEMM, up to 3 concatenated A segments =========
template<int RTR, int KT, int CT>
__global__ __launch_bounds__(256) void wgemm(
    const unsigned short* __restrict__ A0, int w0, int ldA0,
    const unsigned short* __restrict__ A1, int w1, int ldA1,
    const unsigned short* __restrict__ A2, int w2, int ldA2,
    const unsigned short* __restrict__ Bt, int KpB,
    const float* __restrict__ bias,
    unsigned short* __restrict__ C, int ldC,
    int rows, int tiles, int act)
{
  constexpr int Kpad = KT*32;
  constexpr int LD   = Kpad + 8;
  constexpr int NRT  = RTR/16;
  constexpr int CPT  = (RTR*Kpad/8)/256;
  __shared__ __align__(16) unsigned short As[2][RTR*LD];
  int t = threadIdx.x;
  int lane = t & 63, m = lane & 15, q = lane >> 4, w = t >> 6;
  int tileBase = blockIdx.y * (4*CT);
  int rtEnd = (rows + RTR - 1)/RTR;
  int tr = blockIdx.x;
  if (tr >= rtEnd) return;

  short8 breg[CT][KT]; float bv[CT]; bool val[CT]; int colr[CT];
  #pragma unroll
  for (int j=0;j<CT;j++){
    int tt = tileBase + w + 4*j;
    val[j] = (tt < tiles);
    int col = tt*16 + m;
    colr[j] = col;
    bv[j] = 0.f;
    if (val[j]){
      bv[j] = bias[col];
      #pragma unroll
      for (int kt=0;kt<KT;kt++)
        breg[j][kt] = *(const short8*)&Bt[(size_t)col*KpB + kt*32 + q*8];
    } else {
      #pragma unroll
      for (int kt=0;kt<KT;kt++) breg[j][kt] = (short8){0,0,0,0,0,0,0,0};
    }
  }

  int w01 = w0 + w1, w012 = w0 + w1 + w2;
  uint4 r[CPT];
  auto loadRegs = [&](int trr){
    #pragma unroll
    for (int i=0;i<CPT;i++){
      int c = i*256 + t;
      int row = c / (KT*4), kc = (c - row*(KT*4))*8;
      int gr = trr*RTR + row;
      uint4 v = {0,0,0,0};
      if (gr < rows && kc < w012){
        const unsigned short* sp;
        if (kc < w0)       sp = A0 + (size_t)gr*ldA0 + kc;
        else if (kc < w01) sp = A1 + (size_t)gr*ldA1 + (kc - w0);
        else               sp = A2 + (size_t)gr*ldA2 + (kc - w01);
        v = *(const uint4*)sp;
      }
      r[i] = v;
    }
  };
  auto dsw = [&](int p){
    #pragma unroll
    for (int i=0;i<CPT;i++){
      int c = i*256 + t;
      int row = c / (KT*4), kc = (c - row*(KT*4))*8;
      *(uint4*)&As[p][row*LD + kc] = r[i];
    }
  };

  loadRegs(tr);
  dsw(0);
  int p = 0;
  for (;;){
    int nxt = tr + gridDim.x;
    bool hasNext = (nxt < rtEnd);
    if (hasNext) loadRegs(nxt);
    __syncthreads();
    f32x4 acc[NRT][CT] = {};
    #pragma unroll
    for (int kt=0;kt<KT;kt++){
      short8 af[NRT];
      #pragma unroll
      for (int rt=0;rt<NRT;rt++)
        af[rt] = *(const short8*)&As[p][(rt*16+m)*LD + kt*32 + q*8];
      #pragma unroll
      for (int j=0;j<CT;j++)
        #pragma unroll
        for (int rt=0;rt<NRT;rt++)
          acc[rt][j] = __builtin_amdgcn_mfma_f32_16x16x32_bf16(af[rt], breg[j][kt], acc[rt][j], 0,0,0);
    }
    bool tfull = (tr*RTR + RTR <= rows);
#define EPILOG(CHK)                                                         \
    _Pragma("unroll")                                                       \
    for (int rt=0;rt<NRT;rt++){                                             \
      int rbase = tr*RTR + rt*16 + q*4;                                     \
      _Pragma("unroll")                                                     \
      for (int j=0;j<CT;j++){                                               \
        if (!val[j]) continue;                                              \
        _Pragma("unroll")                                                   \
        for (int i=0;i<4;i++){                                              \
          int grow = rbase + i;                                             \
          if (CHK && grow >= rows) continue;                                \
          float v = acc[rt][j][i] + bv[j];                                  \
          if (act == 1) v = fgelu_(v);                                      \
          else if (act == 2) v = ftanh_(v);                                 \
          C[(size_t)grow*ldC + colr[j]] = f2bf(v);                          \
        }                                                                   \
      }                                                                     \
    }
    if (tfull){ EPILOG(false) } else { EPILOG(true) }
#undef EPILOG
    if (!hasNext) break;
    dsw(p^1);
    p ^= 1; tr = nxt;
  }
}

// ---------------- CSR gather + segment max v4: 4 nodes per wave, interleaved chains --
// node ids wave-uniform (readfirstlane): off/edata via scalar loads. Per round, the
// wave issues 4 independent edata s_loads then 16 row loads (4 nodes x 4 edges)
// before consuming any -> 4x the latency chains in flight vs one-node-per-wave.
// Max order per node unchanged -> bit-identical results.
__global__ __launch_bounds__(256) void k_aggregate(
    const int* __restrict__ off, const int* __restrict__ edata,
    const unsigned short* __restrict__ P2, int ldP, int off1,
    unsigned short* __restrict__ agg, int M, int N, int WPN)
{
  int t = threadIdx.x;
  int lane = t & 63, w = t >> 6;
  int nbase, c;
  if (WPN == 1){
    nbase = blockIdx.x*16 + w*4;                 // 16 nodes/block
    c = 2*lane;
  } else {
    nbase = blockIdx.x*8 + (w>>1)*4;             // 8 nodes/block, 2 col-half waves
    c = (w & 1)*80 + 2*lane;
  }
  nbase = __builtin_amdgcn_readfirstlane(nbase);
  if (nbase >= N) return;
  bool act = (lane < 40);
  const float NEG = -__builtin_inff();
  int e[4], e1[4];
  float f0[4], f1[4];
  #pragma unroll
  for (int j=0;j<4;j++){
    int n = nbase + j;
    bool v = (n < N);
    e[j]  = v ? __builtin_amdgcn_readfirstlane(off[n])     : 0;
    e1[j] = v ? __builtin_amdgcn_readfirstlane(off[n + 1]) : 0;
    f0[j] = NEG; f1[j] = NEG;
  }
  for (;;){
    bool cond[4];
    bool any = false;
    #pragma unroll
    for (int j=0;j<4;j++){ cond[j] = (e[j] < e1[j]); any |= cond[j]; }
    if (!any) break;
    unsigned int rr[4][4];
    #pragma unroll
    for (int j=0;j<4;j++){
      if (cond[j]){
        int4 g = *(const int4*)&edata[e[j]];     // uniform addr -> s_load_dwordx4
        int b0 = (g.x>>1)*ldP + (g.x&1)*off1;    // scalar-pipe math
        int b1 = (g.y>>1)*ldP + (g.y&1)*off1;
        int b2 = (g.z>>1)*ldP + (g.z&1)*off1;
        int b3 = (g.w>>1)*ldP + (g.w&1)*off1;
        if (act){
          rr[j][0] = *(const unsigned int*)(P2 + b0 + c);
          rr[j][1] = *(const unsigned int*)(P2 + b1 + c);
          rr[j][2] = *(const unsigned int*)(P2 + b2 + c);
          rr[j][3] = *(const unsigned int*)(P2 + b3 + c);
        }
      }
    }
    #pragma unroll
    for (int j=0;j<4;j++){
      if (cond[j]){
        if (act){
          unsigned int u0 = rr[j][0], u1 = rr[j][1], u2 = rr[j][2], u3 = rr[j][3];
          f0[j] = fmaxf(f0[j], fmaxf(fmaxf(__uint_as_float(u0<<16), __uint_as_float(u1<<16)),
                                     fmaxf(__uint_as_float(u2<<16), __uint_as_float(u3<<16))));
          f1[j] = fmaxf(f1[j], fmaxf(fmaxf(__uint_as_float(u0&0xFFFF0000u), __uint_as_float(u1&0xFFFF0000u)),
                                     fmaxf(__uint_as_float(u2&0xFFFF0000u), __uint_as_float(u3&0xFFFF0000u))));
        }
        e[j] += 4;
      }
    }
  }
  if (act){
    #pragma unroll
    for (int j=0;j<4;j++){
      int n = nbase + j;
      if (n >= N) continue;
      unsigned int o = (__float_as_uint(f0[j] == NEG ? 0.f : f0[j]) >> 16)
                     |  (__float_as_uint(f1[j] == NEG ? 0.f : f1[j]) & 0xFFFF0000u);
      *(unsigned int*)(agg + (size_t)n*M + c) = o;
    }
  }
}

// ---------------- final head ----------------
__global__ void k_head(const unsigned short* __restrict__ h, const int* __restrict__ entry,
                       const float* __restrict__ W1, const float* __restrict__ b1,
                       const float* __restrict__ W2, const float* __restrict__ b2,
                       float* __restrict__ out){
  __shared__ float x[70], x1[70];
  int t = threadIdx.x;
  if (t < 70) x[t] = bf2f(h[(size_t)(*entry)*80 + t]);
  __syncthreads();
  if (t < 70){
    float s = b1[t];
    for (int i=0;i<70;i++) s += x[i]*W1[i*70 + t];
    x1[t] = fmaxf(s, 0.f);
  }
  __syncthreads();
  if (t < 640){
    float s = b2[t];
    for (int i=0;i<70;i++) s += x1[i]*W2[i*640 + t];
    out[t] = s;
  }
}

extern "C" void kernel_launch(void* const* d_in, const int* in_sizes, int n_in,
                              void* d_out, int out_size, void* d_ws, size_t ws_size,
                              hipStream_t stream) {
  const int*   tokens   = (const int*)d_in[0];
  const int*   type_idx = (const int*)d_in[1];
  const int*   esrc     = (const int*)d_in[2];
  const int*   edst     = (const int*)d_in[3];
  const int*   entry    = (const int*)d_in[4];
  const float* embed    = (const float*)d_in[5];
  const float* Wi_map   = (const float*)d_in[6];
  const float* Wh_map   = (const float*)d_in[7];
  const float* bi_map   = (const float*)d_in[8];
  const float* bh_map   = (const float*)d_in[9];
  const float* Wi_mem   = (const float*)d_in[10];
  const float* Wh_mem   = (const float*)d_in[11];
  const float* bi_mem   = (const float*)d_in[12];
  const float* bh_mem   = (const float*)d_in[13];
  const float* Wm_plain = (const float*)d_in[14];
  const float* bm_plain = (const float*)d_in[15];
  const float* Wu_plain = (const float*)d_in[16];
  const float* bu_plain = (const float*)d_in[17];
  const float* Wm_ar    = (const float*)d_in[18];
  const float* bm_ar    = (const float*)d_in[19];
  const float* Wu_ar    = (const float*)d_in[20];
  const float* bu_ar    = (const float*)d_in[21];
  const float* W1 = (const float*)d_in[22];
  const float* b1 = (const float*)d_in[23];
  const float* W2 = (const float*)d_in[24];
  const float* b2 = (const float*)d_in[25];
  float* out = (float*)d_out;

  const int N  = in_sizes[1];      // 100000
  const int TE = in_sizes[2];      // 500000
  const int E  = TE / 2;
  const int V64 = in_sizes[5];     // V*DE = 640000

  char* p = (char*)d_ws;
  auto alloc = [&](size_t bytes)->char* { char* r = p; p += (bytes + 255) & ~(size_t)255; return r; };
  unsigned short* hA  = (unsigned short*)alloc((size_t)N*80*2);
  unsigned short* hB  = (unsigned short*)alloc((size_t)N*80*2);
  unsigned short* hC  = (unsigned short*)alloc((size_t)N*80*2);
  unsigned short* P2  = (unsigned short*)alloc((size_t)N*320*2);
  unsigned short* agg = (unsigned short*)alloc((size_t)N*160*2);
  int* deg    = (int*)alloc((size_t)N*4);
  int* curp   = (int*)alloc((size_t)N*4);
  int* off    = (int*)alloc((size_t)(N+8)*4);
  int* edata  = (int*)alloc((size_t)(TE + 4*N + 16)*4);            // padded CSR
  int* sbsum  = (int*)alloc(256*4);
  int* cnt    = (int*)alloc(16*4);
  int* idxcat = (int*)alloc((size_t)R2*4);
  unsigned short* BtA  = (unsigned short*)alloc(388096*2);
  float* biasA = (float*)alloc(2752*4);
  unsigned short* embB = (unsigned short*)alloc((size_t)V64*2);

  hipMemsetAsync(idxcat, 0xFF, (size_t)R2*4, stream);
  hipMemsetAsync(cnt,    0,    16*4, stream);
  hipMemsetAsync(deg,    0,    (size_t)N*4, stream);
  hipMemsetAsync(curp,   0,    (size_t)N*4, stream);

  k_prepB<<<dim3(8,18), 256, 0, stream>>>(Wm_plain, Wu_plain, Wm_ar, Wu_ar,
                                          Wi_map, Wh_map, Wi_mem, Wh_mem, BtA);
  k_prepBias<<<1, 256, 0, stream>>>(bm_plain, bu_plain, bm_ar, bu_ar,
                                    bi_map, bh_map, bi_mem, bh_mem, biasA);
  k_prepEmb<<<(V64+255)/256, 256, 0, stream>>>(embed, embB, V64);
  k_init_h<<<(N*80+255)/256, 256, 0, stream>>>(type_idx, hA, N);
  k_compact<<<(N+255)/256, 256, 0, stream>>>(type_idx, idxcat, cnt, N);

  k_count<<<(TE+255)/256, 256, 0, stream>>>(edst, deg, TE);
  int nb = (N + 2047)/2048;
  k_scan1<<<nb, 256, 0, stream>>>(deg, off, sbsum, N);
  k_scan2<<<1, 64, 0, stream>>>(sbsum, nb);
  k_scan3<<<(N+255)/256, 256, 0, stream>>>(off, sbsum, N, nb);
  k_fill<<<(TE+255)/256, 256, 0, stream>>>(esrc, edst, off, curp, edata, TE, E);
  k_pad<<<(N+255)/256, 256, 0, stream>>>(off, curp, edata, N);

  // ---- GRU: one persistent launch (8 steps internal), gather+scatter fused ----
  kgru<<<dim3(CAPT/GRR, 2), 256, 0, stream>>>(
      idxcat, tokens, embB,
      BtA + 322560, BtA + 322560 + 32768,
      biasA + 2240, biasA + 2240 + 256, hA);

  // ---- 2 blocks x (3 plain MP + concat-residual AR MP) ----
  unsigned short* cur = hA; unsigned short* f1 = hB; unsigned short* f2 = hC;
  int li = 0;
  for (int blk = 0; blk < 2; blk++){
    unsigned short* saved = cur;
    unsigned short* ins[3]  = {cur, f1, f2};
    unsigned short* outs[3] = {f1, f2, f1};
    for (int j = 0; j < 3; j++){
      unsigned short* X = ins[j]; unsigned short* Yo = outs[j];
      // msg: [N,80] @ [96->160] (both edge types fused in cols)
      wgemm<64,3,3><<<dim3(1024,1), 256, 0, stream>>>(
          X, 80, 80,  nullptr, 0, 0,  nullptr, 0, 0,
          BtA + li*15360, 96, biasA + li*160,
          P2, 160, N, 10, 0);
      k_aggregate<<<(N+15)/16, 256, 0, stream>>>(off, edata, P2, 160, 80, agg, 80, N, 1);
      // upd: [N,80|80] @ [160->80]
      wgemm<64,5,2><<<dim3(1024,1), 256, 0, stream>>>(
          X, 80, 80,  agg, 80, 80,  nullptr, 0, 0,
          BtA + 92160 + li*12800, 160, biasA + 960 + li*80,
          Yo, 80, N, 5, 0);
      li++;
    }
    // AR msg: [N,80|80] @ [160->320], gelu; y splits 20 col tiles into 12+8
    wgemm<64,5,3><<<dim3(512,2), 256, 0, stream>>>(
        saved, 80, 80,  f1, 80, 80,  nullptr, 0, 0,
        BtA + 168960 + blk*51200, 160, biasA + 1440 + blk*320,
        P2, 320, N, 20, 1 /*gelu*/);
    k_aggregate<<<(N+7)/8, 256, 0, stream>>>(off, edata, P2, 320, 160, agg, 160, N, 2);
    // AR upd: [N,80|80|160] @ [320->80], tanh; 32-row tiles (K=320 LDS)
    wgemm<32,10,2><<<dim3(1024,1), 256, 0, stream>>>(
        saved, 80, 80,  f1, 80, 80,  agg, 160, 160,
        BtA + 271360 + blk*25600, 320, biasA + 2080 + blk*80,
        f2, 80, N, 5, 2 /*tanh*/);
    unsigned short* t3 = cur; cur = f2; f2 = t3;
  }

  k_head<<<1, 640, 0, stream>>>(cur, entry, W1, b1, W2, b2, out);
}

// Round 13
// 866.840 us; speedup vs baseline: 1.0974x; 1.0766x over previous
//
#include <hip/hip_runtime.h>
#include <math.h>

#define CAPT 20480              // per-type compacted-node capacity (actual ~16.7k)
#define R2   (2*CAPT)
#define GLD  136                // kgru LDS row stride (ushorts): breaks pow2 banking
#define GRR  32                 // kgru rows per block

typedef __attribute__((ext_vector_type(8))) short short8;
typedef __attribute__((ext_vector_type(4))) float f32x4;

// ---- fast transcendentals: v_exp_f32 / v_rcp_f32 based; err ~1e-7 << bf16 ulp ----
__device__ __forceinline__ float fexp2_(float x){ return __builtin_amdgcn_exp2f(x); }
__device__ __forceinline__ float frcp_(float x){ return __builtin_amdgcn_rcpf(x); }
__device__ __forceinline__ float ftanh_(float x){
  float ax = __builtin_fabsf(x);
  float t = fexp2_(-2.885390082f * ax);          // e^{-2|x|}
  float r = (1.f - t) * frcp_(1.f + t);
  return __builtin_copysignf(r, x);
}
__device__ __forceinline__ float fsig_(float x){
  return frcp_(1.f + fexp2_(-1.442695041f * x));
}
__device__ __forceinline__ float fgelu_(float x){
  const float c = 0.7978845608028654f;
  return 0.5f*x*(1.f + ftanh_(c*(x + 0.044715f*x*x*x)));
}
__device__ __forceinline__ unsigned short f2bf(float x){
  unsigned int u = __float_as_uint(x);
  return (unsigned short)((u + 0x7FFFu + ((u>>16)&1u)) >> 16);
}
__device__ __forceinline__ float bf2f(unsigned short v){
  return __uint_as_float(((unsigned int)v) << 16);
}

// ---------------- weight prep: transposed bf16 B arena, padded to 16-mult segments ----
// Arena layout (bf16 elems):
//  [0..6)      plain msg li:  [160][96]   off = li*15360
//  [6..12)     plain upd li:  [80][160]   off = 92160 + li*12800
//  [12..14)    ar msg blk:    [320][160]  off = 168960 + blk*51200
//  [14..16)    ar upd blk:    [80][320]   off = 271360 + blk*25600
//  [16..18)    gru typ:       [256][128]  off = 322560 + typ*32768
__global__ void k_prepB(const float* __restrict__ Wm_plain, const float* __restrict__ Wu_plain,
                        const float* __restrict__ Wm_ar, const float* __restrict__ Wu_ar,
                        const float* __restrict__ Wi_map, const float* __restrict__ Wh_map,
                        const float* __restrict__ Wi_mem, const float* __restrict__ Wh_mem,
                        unsigned short* __restrict__ BtArena){
  int id = blockIdx.y;
  int Kp, elems, off;
  if (id < 6){ Kp=96;  elems=15360; off=id*15360; }
  else if (id < 12){ Kp=160; elems=12800; off=92160+(id-6)*12800; }
  else if (id < 14){ Kp=160; elems=51200; off=168960+(id-12)*51200; }
  else if (id < 16){ Kp=320; elems=25600; off=271360+(id-14)*25600; }
  else { Kp=128; elems=32768; off=322560+(id-16)*32768; }
  for (int g = blockIdx.x*256 + threadIdx.x; g < elems; g += 8*256){
    int c = g / Kp, k = g - c*Kp;
    float val = 0.f;
    if (id < 6){
      int li = id; int t = (c >= 80); int cc = c - t*80;
      if (cc < 70 && k < 70) val = Wm_plain[((li*2+t)*70 + k)*70 + cc];
    } else if (id < 12){
      int li = id-6;
      int kk = (k < 70) ? k : ((k >= 80 && k < 150) ? 70 + (k-80) : -1);
      if (c < 70 && kk >= 0) val = Wu_plain[(li*140 + kk)*70 + c];
    } else if (id < 14){
      int blk = id-12; int t = (c >= 160); int cc = c - t*160;
      int kk = (k < 70) ? k : ((k >= 80 && k < 150) ? 70 + (k-80) : -1);
      if (cc < 140 && kk >= 0) val = Wm_ar[(((blk*2+t)*140) + kk)*140 + cc];
    } else if (id < 16){
      int blk = id-14;
      int kk = (k < 70) ? k : ((k >= 80 && k < 150) ? 70 + (k-80)
               : ((k >= 160 && k < 300) ? 140 + (k-160) : -1));
      if (c < 70 && kk >= 0) val = Wu_ar[(blk*280 + kk)*70 + c];
    } else {
      int typ = id-16;
      const float* Wi = typ ? Wi_mem : Wi_map;
      const float* Wh = typ ? Wh_mem : Wh_map;
      if (c < 192) val = (k < 64) ? Wi[c*64 + k] : Wh[c*64 + (k-64)];
      else { int cc = c-192; val = (k >= 64) ? Wh[(128+cc)*64 + (k-64)] : 0.f; }
    }
    BtArena[off + g] = f2bf(val);
  }
}

// bias arena (fp32): [0..960) plain msg [160]x6; [960..1440) plain upd [80]x6;
// [1440..2080) ar msg [320]x2; [2080..2240) ar upd [80]x2; [2240..2752) gru [256]x2
__global__ void k_prepBias(const float* __restrict__ bm_plain, const float* __restrict__ bu_plain,
                           const float* __restrict__ bm_ar, const float* __restrict__ bu_ar,
                           const float* __restrict__ bi_map, const float* __restrict__ bh_map,
                           const float* __restrict__ bi_mem, const float* __restrict__ bh_mem,
                           float* __restrict__ biasA){
  for (int g = threadIdx.x; g < 2752; g += 256){
    float val = 0.f;
    if (g < 960){ int li=g/160, c=g%160; int t=(c>=80); int cc=c-t*80;
      if (cc<70) val = bm_plain[(li*2+t)*70 + cc]; }
    else if (g < 1440){ int u=g-960; int li=u/80, c=u%80; if (c<70) val = bu_plain[li*70+c]; }
    else if (g < 2080){ int u=g-1440; int blk=u/320, c=u%320; int t=(c>=160); int cc=c-t*160;
      if (cc<140) val = bm_ar[(blk*2+t)*140 + cc]; }
    else if (g < 2240){ int u=g-2080; int blk=u/80, c=u%80; if (c<70) val = bu_ar[blk*70+c]; }
    else { int u=g-2240; int typ=u/256, c=u%256;
      const float* bi = typ ? bi_mem : bi_map; const float* bh = typ ? bh_mem : bh_map;
      val = (c < 192) ? (bi[c]+bh[c]) : bh[128 + (c-192)]; }
    biasA[g] = val;
  }
}

// ---------------- embed -> bf16 table (1.28 MB, L2-resident for the gather) ----------
__global__ void k_prepEmb(const float* __restrict__ embed, unsigned short* __restrict__ embB,
                          int total){
  int g = blockIdx.x*256 + threadIdx.x;
  if (g < total) embB[g] = f2bf(embed[g]);
}

// ---------------- init h = [one_hot(type,6) | zeros] bf16, stride 80 ----------------
__global__ void k_init_h(const int* __restrict__ type_idx, unsigned short* __restrict__ h, int N){
  int g = blockIdx.x*256 + threadIdx.x;
  if (g >= N*80) return;
  int n = g / 80, c = g - n*80;
  h[g] = (c < 6 && type_idx[n] == c) ? (unsigned short)0x3F80 : (unsigned short)0;
}

__global__ void k_compact(const int* __restrict__ type_idx, int* __restrict__ idxcat,
                          int* __restrict__ cnt, int N){
  int n = blockIdx.x*256 + threadIdx.x;
  if (n >= N) return;
  int t = type_idx[n];
  if (t == 0){ int p = atomicAdd(&cnt[0],1); if (p < CAPT) idxcat[p] = n; }
  else if (t == 5){ int p = atomicAdd(&cnt[1],1); if (p < CAPT) idxcat[CAPT+p] = n; }
}

// ---------------- CSR build, per-node edge count padded to multiple of 4 -------------
__global__ void k_count(const int* __restrict__ edst, int* __restrict__ deg, int TE){
  int i = blockIdx.x*256 + threadIdx.x;
  if (i < TE) atomicAdd(&deg[edst[i]], 1);
}
__global__ void k_scan1(const int* __restrict__ deg, int* __restrict__ off,
                        int* __restrict__ bsum, int N){
  __shared__ int sh[256];
  int t = threadIdx.x; int base = blockIdx.x*2048;
  int v[8]; int s = 0;
  for (int i=0;i<8;i++){
    int g = base + t*8 + i;
    int x = (g<N)? (((deg[g]+3)>>2)<<2) : 0;     // pad to x4
    v[i]=x; s+=x;
  }
  sh[t]=s; __syncthreads();
  for (int o=1;o<256;o<<=1){ int x = (t>=o)? sh[t-o]:0; __syncthreads(); sh[t]+=x; __syncthreads(); }
  if (t==255) bsum[blockIdx.x] = sh[255];
  int run = sh[t]-s;
  for (int i=0;i<8;i++){ int g = base + t*8 + i; if (g<N) off[g]=run; run+=v[i]; }
}
__global__ void k_scan2(int* bsum, int nb){
  if (threadIdx.x==0 && blockIdx.x==0){
    int run=0;
    for(int b=0;b<nb;b++){ int x=bsum[b]; bsum[b]=run; run+=x; }
    bsum[nb]=run;                                 // grand total (padded)
  }
}
__global__ void k_scan3(int* __restrict__ off, const int* __restrict__ bsum, int N, int nb){
  int g = blockIdx.x*256+threadIdx.x;
  if (g < N) off[g] += bsum[g>>11];
  if (g == 0) off[N] = bsum[nb];
}
__global__ void k_fill(const int* __restrict__ esrc, const int* __restrict__ edst,
                       const int* __restrict__ off, int* __restrict__ cur,
                       int* __restrict__ edata, int TE, int E){
  int i = blockIdx.x*256 + threadIdx.x;
  if (i >= TE) return;
  int d = edst[i];
  int pos = off[d] + atomicAdd(&cur[d], 1);
  edata[pos] = (esrc[i] << 1) | (i >= E ? 1 : 0);
}
// pad slots [deg, deg4) with a duplicate of the node's first edge (idempotent for max)
__global__ void k_pad(const int* __restrict__ off, const int* __restrict__ cur,
                      int* __restrict__ edata, int N){
  int n = blockIdx.x*256 + threadIdx.x;
  if (n >= N) return;
  int d = cur[n];
  if (d == 0) return;
  int d4 = ((d+3)>>2)<<2;
  int base = off[n];
  int first = edata[base];
  for (int i = d; i < d4; i++) edata[base+i] = first;
}

// ======== kgru v3: persistent GRU — 32-row blocks, dbuf, 1 barrier/step ============
__global__ __launch_bounds__(256) void kgru(
    const int* __restrict__ idxcat, const int* __restrict__ tokens,
    const unsigned short* __restrict__ embB,
    const unsigned short* __restrict__ Bt, const unsigned short* __restrict__ Bt2,
    const float* __restrict__ bias, const float* __restrict__ bias2,
    unsigned short* __restrict__ hOut)
{
  __shared__ __align__(16) unsigned short As[2][GRR*GLD];
  __shared__ int tokS[GRR*8];
  __shared__ int idxS[GRR];
  int rb = blockIdx.y * CAPT + blockIdx.x * GRR;
  if (idxcat[rb] < 0) return;                      // all-pad block
  int t = threadIdx.x;
  int lane = t & 63, m = lane & 15, q = lane >> 4, w = t >> 6;
  const unsigned short* Bsel = blockIdx.y ? Bt2 : Bt;
  const float* bsel = blockIdx.y ? bias2 : bias;
  short8 breg[4][4]; float bv[4];
  #pragma unroll
  for (int j=0;j<4;j++){
    int col = (w + 4*j)*16 + m;
    bv[j] = bsel[col];
    #pragma unroll
    for (int kt=0;kt<4;kt++)
      breg[j][kt] = *(const short8*)&Bsel[(size_t)col*128 + kt*32 + q*8];
  }
  if (t < GRR) idxS[t] = idxcat[rb + t];
  if (t < GRR*8){
    int nd = idxcat[rb + (t>>3)]; if (nd < 0) nd = 0;
    tokS[t] = tokens[nd*8 + (t & 7)];
  }
  __syncthreads();                                 // tokS ready
  if (t < GRR*8){
    int row = t >> 3, ch = t & 7;
    *(uint4*)&As[0][row*GLD + ch*8] = *(const uint4*)&embB[(size_t)tokS[row*8]*64 + ch*8];
  }
  for (int j = t; j < GRR*32; j += 256){
    int row = j >> 5, k2 = (j & 31)*2;
    *(unsigned int*)&As[0][row*GLD + 64 + k2] = 0;
  }
  __syncthreads();
  unsigned short hreg[2][4];
  #pragma unroll
  for (int rt=0;rt<2;rt++)
    #pragma unroll
    for (int i=0;i<4;i++) hreg[rt][i] = 0;
  int u = w*16 + m;
  int p = 0;
  for (int s = 0; s < 8; s++){
    uint4 xr;
    if (s < 7 && t < GRR*8){                       // prefetch X(s+1) early (global)
      int row = t >> 3, ch = t & 7;
      xr = *(const uint4*)&embB[(size_t)tokS[row*8 + s + 1]*64 + ch*8];
    }
    f32x4 acc[2][4] = {};
    #pragma unroll
    for (int kt=0;kt<4;kt++){
      short8 af[2];
      #pragma unroll
      for (int rt=0;rt<2;rt++)
        af[rt] = *(const short8*)&As[p][(rt*16+m)*GLD + kt*32 + q*8];
      #pragma unroll
      for (int j=0;j<4;j++)
        #pragma unroll
        for (int rt=0;rt<2;rt++)
          acc[rt][j] = __builtin_amdgcn_mfma_f32_16x16x32_bf16(af[rt], breg[j][kt], acc[rt][j], 0,0,0);
    }
    #pragma unroll
    for (int rt=0;rt<2;rt++){
      #pragma unroll
      for (int i=0;i<4;i++){
        float rr = fsig_(acc[rt][0][i] + bv[0]);
        float zz = fsig_(acc[rt][1][i] + bv[1]);
        float hn = acc[rt][3][i] + bv[3];
        float nn = ftanh_(acc[rt][2][i] + bv[2] + (rr - 1.f)*hn);
        float hp = bf2f(hreg[rt][i]);
        hreg[rt][i] = f2bf((1.f - zz)*nn + zz*hp);
      }
    }
    if (s < 7){
      #pragma unroll
      for (int rt=0;rt<2;rt++)
        #pragma unroll
        for (int i=0;i<4;i++)
          As[p^1][(rt*16 + q*4 + i)*GLD + 64 + u] = hreg[rt][i];
      if (t < GRR*8){
        int row = t >> 3, ch = t & 7;
        *(uint4*)&As[p^1][row*GLD + ch*8] = xr;
      }
      __syncthreads();
      p ^= 1;
    } else {
      #pragma unroll
      for (int rt=0;rt<2;rt++)
        #pragma unroll
        for (int i=0;i<4;i++){
          int nd = idxS[rt*16 + q*4 + i];
          if (nd >= 0) hOut[(size_t)nd*80 + 6 + u] = hreg[rt][i];
        }
    }
  }
}

// ======== wgemm: B-in-registers MFMA GEMM, up to 3 concatenated A segments =========
// LDS: UNPADDED row stride (keeps 4 blocks/CU at KT=5/10 — the +8 pad cost 25% occ);
// bank conflicts broken instead by XOR chunk swizzle: 16B chunk ch of row r is
// stored at ch^(r&3). Fragment reads go 8-way -> 4-way aliased; global coalescing
// and LDS writes unchanged (permutation within 64B groups).
template<int RTR, int KT, int CT>
__global__ __launch_bounds__(256) void wgemm(
    const unsigned short* __restrict__ A0, int w0, int ldA0,
    const unsigned short* __restrict__ A1, int w1, int ldA1,
    const unsigned short* __restrict__ A2, int w2, int ldA2,
    const unsigned short* __restrict__ Bt, int KpB,
    const float* __restrict__ bias,
    unsigned short* __restrict__ C, int ldC,
    int rows, int tiles, int act)
{
  constexpr int Kpad = KT*32;
  constexpr int NRT  = RTR/16;
  constexpr int CPT  = (RTR*Kpad/8)/256;
  __shared__ __align__(16) unsigned short As[2][RTR*Kpad];
  int t = threadIdx.x;
  int lane = t & 63, m = lane & 15, q = lane >> 4, w = t >> 6;
  int tileBase = blockIdx.y * (4*CT);
  int rtEnd = (rows + RTR - 1)/RTR;
  int tr = blockIdx.x;
  if (tr >= rtEnd) return;

  short8 breg[CT][KT]; float bv[CT]; bool val[CT]; int colr[CT];
  #pragma unroll
  for (int j=0;j<CT;j++){
    int tt = tileBase + w + 4*j;
    val[j] = (tt < tiles);
    int col = tt*16 + m;
    colr[j] = col;
    bv[j] = 0.f;
    if (val[j]){
      bv[j] = bias[col];
      #pragma unroll
      for (int kt=0;kt<KT;kt++)
        breg[j][kt] = *(const short8*)&Bt[(size_t)col*KpB + kt*32 + q*8];
    } else {
      #pragma unroll
      for (int kt=0;kt<KT;kt++) breg[j][kt] = (short8){0,0,0,0,0,0,0,0};
    }
  }

  int w01 = w0 + w1, w012 = w0 + w1 + w2;
  uint4 r[CPT];
  auto loadRegs = [&](int trr){
    #pragma unroll
    for (int i=0;i<CPT;i++){
      int c = i*256 + t;
      int row = c / (KT*4), kc = (c - row*(KT*4))*8;
      int gr = trr*RTR + row;
      uint4 v = {0,0,0,0};
      if (gr < rows && kc < w012){
        const unsigned short* sp;
        if (kc < w0)       sp = A0 + (size_t)gr*ldA0 + kc;
        else if (kc < w01) sp = A1 + (size_t)gr*ldA1 + (kc - w0);
        else               sp = A2 + (size_t)gr*ldA2 + (kc - w01);
        v = *(const uint4*)sp;
      }
      r[i] = v;
    }
  };
  auto dsw = [&](int p){
    #pragma unroll
    for (int i=0;i<CPT;i++){
      int c = i*256 + t;
      int row = c / (KT*4), ch = c - row*(KT*4);
      int phys = ch ^ (row & 3);                  // XOR swizzle (chunk count %4==0)
      *(uint4*)&As[p][row*Kpad + phys*8] = r[i];
    }
  };

  loadRegs(tr);
  dsw(0);
  int p = 0;
  for (;;){
    int nxt = tr + gridDim.x;
    bool hasNext = (nxt < rtEnd);
    if (hasNext) loadRegs(nxt);
    __syncthreads();
    f32x4 acc[NRT][CT] = {};
    #pragma unroll
    for (int kt=0;kt<KT;kt++){
      short8 af[NRT];
      #pragma unroll
      for (int rt=0;rt<NRT;rt++)
        af[rt] = *(const short8*)&As[p][(rt*16+m)*Kpad + (((kt*4+q) ^ (m&3))*8)];
      #pragma unroll
      for (int j=0;j<CT;j++)
        #pragma unroll
        for (int rt=0;rt<NRT;rt++)
          acc[rt][j] = __builtin_amdgcn_mfma_f32_16x16x32_bf16(af[rt], breg[j][kt], acc[rt][j], 0,0,0);
    }
    bool tfull = (tr*RTR + RTR <= rows);
#define EPILOG(CHK)                                                         \
    _Pragma("unroll")                                                       \
    for (int rt=0;rt<NRT;rt++){                                             \
      int rbase = tr*RTR + rt*16 + q*4;                                     \
      _Pragma("unroll")                                                     \
      for (int j=0;j<CT;j++){                                               \
        if (!val[j]) continue;                                              \
        _Pragma("unroll")                                                   \
        for (int i=0;i<4;i++){                                              \
          int grow = rbase + i;                                             \
          if (CHK && grow >= rows) continue;                                \
          float v = acc[rt][j][i] + bv[j];                                  \
          if (act == 1) v = fgelu_(v);                                      \
          else if (act == 2) v = ftanh_(v);                                 \
          C[(size_t)grow*ldC + colr[j]] = f2bf(v);                          \
        }                                                                   \
      }                                                                     \
    }
    if (tfull){ EPILOG(false) } else { EPILOG(true) }
#undef EPILOG
    if (!hasNext) break;
    dsw(p^1);
    p ^= 1; tr = nxt;
  }
}

// ---------------- CSR gather + segment max v4: 4 nodes per wave, interleaved chains --
__global__ __launch_bounds__(256) void k_aggregate(
    const int* __restrict__ off, const int* __restrict__ edata,
    const unsigned short* __restrict__ P2, int ldP, int off1,
    unsigned short* __restrict__ agg, int M, int N, int WPN)
{
  int t = threadIdx.x;
  int lane = t & 63, w = t >> 6;
  int nbase, c;
  if (WPN == 1){
    nbase = blockIdx.x*16 + w*4;                 // 16 nodes/block
    c = 2*lane;
  } else {
    nbase = blockIdx.x*8 + (w>>1)*4;             // 8 nodes/block, 2 col-half waves
    c = (w & 1)*80 + 2*lane;
  }
  nbase = __builtin_amdgcn_readfirstlane(nbase);
  if (nbase >= N) return;
  bool act = (lane < 40);
  const float NEG = -__builtin_inff();
  int e[4], e1[4];
  float f0[4], f1[4];
  #pragma unroll
  for (int j=0;j<4;j++){
    int n = nbase + j;
    bool v = (n < N);
    e[j]  = v ? __builtin_amdgcn_readfirstlane(off[n])     : 0;
    e1[j] = v ? __builtin_amdgcn_readfirstlane(off[n + 1]) : 0;
    f0[j] = NEG; f1[j] = NEG;
  }
  for (;;){
    bool cond[4];
    bool any = false;
    #pragma unroll
    for (int j=0;j<4;j++){ cond[j] = (e[j] < e1[j]); any |= cond[j]; }
    if (!any) break;
    unsigned int rr[4][4];
    #pragma unroll
    for (int j=0;j<4;j++){
      if (cond[j]){
        int4 g = *(const int4*)&edata[e[j]];     // uniform addr -> s_load_dwordx4
        int b0 = (g.x>>1)*ldP + (g.x&1)*off1;    // scalar-pipe math
        int b1 = (g.y>>1)*ldP + (g.y&1)*off1;
        int b2 = (g.z>>1)*ldP + (g.z&1)*off1;
        int b3 = (g.w>>1)*ldP + (g.w&1)*off1;
        if (act){
          rr[j][0] = *(const unsigned int*)(P2 + b0 + c);
          rr[j][1] = *(const unsigned int*)(P2 + b1 + c);
          rr[j][2] = *(const unsigned int*)(P2 + b2 + c);
          rr[j][3] = *(const unsigned int*)(P2 + b3 + c);
        }
      }
    }
    #pragma unroll
    for (int j=0;j<4;j++){
      if (cond[j]){
        if (act){
          unsigned int u0 = rr[j][0], u1 = rr[j][1], u2 = rr[j][2], u3 = rr[j][3];
          f0[j] = fmaxf(f0[j], fmaxf(fmaxf(__uint_as_float(u0<<16), __uint_as_float(u1<<16)),
                                     fmaxf(__uint_as_float(u2<<16), __uint_as_float(u3<<16))));
          f1[j] = fmaxf(f1[j], fmaxf(fmaxf(__uint_as_float(u0&0xFFFF0000u), __uint_as_float(u1&0xFFFF0000u)),
                                     fmaxf(__uint_as_float(u2&0xFFFF0000u), __uint_as_float(u3&0xFFFF0000u))));
        }
        e[j] += 4;
      }
    }
  }
  if (act){
    #pragma unroll
    for (int j=0;j<4;j++){
      int n = nbase + j;
      if (n >= N) continue;
      unsigned int o = (__float_as_uint(f0[j] == NEG ? 0.f : f0[j]) >> 16)
                     |  (__float_as_uint(f1[j] == NEG ? 0.f : f1[j]) & 0xFFFF0000u);
      *(unsigned int*)(agg + (size_t)n*M + c) = o;
    }
  }
}

// ---------------- final head ----------------
__global__ void k_head(const unsigned short* __restrict__ h, const int* __restrict__ entry,
                       const float* __restrict__ W1, const float* __restrict__ b1,
                       const float* __restrict__ W2, const float* __restrict__ b2,
                       float* __restrict__ out){
  __shared__ float x[70], x1[70];
  int t = threadIdx.x;
  if (t < 70) x[t] = bf2f(h[(size_t)(*entry)*80 + t]);
  __syncthreads();
  if (t < 70){
    float s = b1[t];
    for (int i=0;i<70;i++) s += x[i]*W1[i*70 + t];
    x1[t] = fmaxf(s, 0.f);
  }
  __syncthreads();
  if (t < 640){
    float s = b2[t];
    for (int i=0;i<70;i++) s += x1[i]*W2[i*640 + t];
    out[t] = s;
  }
}

extern "C" void kernel_launch(void* const* d_in, const int* in_sizes, int n_in,
                              void* d_out, int out_size, void* d_ws, size_t ws_size,
                              hipStream_t stream) {
  const int*   tokens   = (const int*)d_in[0];
  const int*   type_idx = (const int*)d_in[1];
  const int*   esrc     = (const int*)d_in[2];
  const int*   edst     = (const int*)d_in[3];
  const int*   entry    = (const int*)d_in[4];
  const float* embed    = (const float*)d_in[5];
  const float* Wi_map   = (const float*)d_in[6];
  const float* Wh_map   = (const float*)d_in[7];
  const float* bi_map   = (const float*)d_in[8];
  const float* bh_map   = (const float*)d_in[9];
  const float* Wi_mem   = (const float*)d_in[10];
  const float* Wh_mem   = (const float*)d_in[11];
  const float* bi_mem   = (const float*)d_in[12];
  const float* bh_mem   = (const float*)d_in[13];
  const float* Wm_plain = (const float*)d_in[14];
  const float* bm_plain = (const float*)d_in[15];
  const float* Wu_plain = (const float*)d_in[16];
  const float* bu_plain = (const float*)d_in[17];
  const float* Wm_ar    = (const float*)d_in[18];
  const float* bm_ar    = (const float*)d_in[19];
  const float* Wu_ar    = (const float*)d_in[20];
  const float* bu_ar    = (const float*)d_in[21];
  const float* W1 = (const float*)d_in[22];
  const float* b1 = (const float*)d_in[23];
  const float* W2 = (const float*)d_in[24];
  const float* b2 = (const float*)d_in[25];
  float* out = (float*)d_out;

  const int N  = in_sizes[1];      // 100000
  const int TE = in_sizes[2];      // 500000
  const int E  = TE / 2;
  const int V64 = in_sizes[5];     // V*DE = 640000

  char* p = (char*)d_ws;
  auto alloc = [&](size_t bytes)->char* { char* r = p; p += (bytes + 255) & ~(size_t)255; return r; };
  unsigned short* hA  = (unsigned short*)alloc((size_t)N*80*2);
  unsigned short* hB  = (unsigned short*)alloc((size_t)N*80*2);
  unsigned short* hC  = (unsigned short*)alloc((size_t)N*80*2);
  unsigned short* P2  = (unsigned short*)alloc((size_t)N*320*2);
  unsigned short* agg = (unsigned short*)alloc((size_t)N*160*2);
  int* deg    = (int*)alloc((size_t)N*4);
  int* curp   = (int*)alloc((size_t)N*4);
  int* off    = (int*)alloc((size_t)(N+8)*4);
  int* edata  = (int*)alloc((size_t)(TE + 4*N + 16)*4);            // padded CSR
  int* sbsum  = (int*)alloc(256*4);
  int* cnt    = (int*)alloc(16*4);
  int* idxcat = (int*)alloc((size_t)R2*4);
  unsigned short* BtA  = (unsigned short*)alloc(388096*2);
  float* biasA = (float*)alloc(2752*4);
  unsigned short* embB = (unsigned short*)alloc((size_t)V64*2);

  hipMemsetAsync(idxcat, 0xFF, (size_t)R2*4, stream);
  hipMemsetAsync(cnt,    0,    16*4, stream);
  hipMemsetAsync(deg,    0,    (size_t)N*4, stream);
  hipMemsetAsync(curp,   0,    (size_t)N*4, stream);

  k_prepB<<<dim3(8,18), 256, 0, stream>>>(Wm_plain, Wu_plain, Wm_ar, Wu_ar,
                                          Wi_map, Wh_map, Wi_mem, Wh_mem, BtA);
  k_prepBias<<<1, 256, 0, stream>>>(bm_plain, bu_plain, bm_ar, bu_ar,
                                    bi_map, bh_map, bi_mem, bh_mem, biasA);
  k_prepEmb<<<(V64+255)/256, 256, 0, stream>>>(embed, embB, V64);
  k_init_h<<<(N*80+255)/256, 256, 0, stream>>>(type_idx, hA, N);
  k_compact<<<(N+255)/256, 256, 0, stream>>>(type_idx, idxcat, cnt, N);

  k_count<<<(TE+255)/256, 256, 0, stream>>>(edst, deg, TE);
  int nb = (N + 2047)/2048;
  k_scan1<<<nb, 256, 0, stream>>>(deg, off, sbsum, N);
  k_scan2<<<1, 64, 0, stream>>>(sbsum, nb);
  k_scan3<<<(N+255)/256, 256, 0, stream>>>(off, sbsum, N, nb);
  k_fill<<<(TE+255)/256, 256, 0, stream>>>(esrc, edst, off, curp, edata, TE, E);
  k_pad<<<(N+255)/256, 256, 0, stream>>>(off, curp, edata, N);

  // ---- GRU: one persistent launch (8 steps internal), gather+scatter fused ----
  kgru<<<dim3(CAPT/GRR, 2), 256, 0, stream>>>(
      idxcat, tokens, embB,
      BtA + 322560, BtA + 322560 + 32768,
      biasA + 2240, biasA + 2240 + 256, hA);

  // ---- 2 blocks x (3 plain MP + concat-residual AR MP) ----
  unsigned short* cur = hA; unsigned short* f1 = hB; unsigned short* f2 = hC;
  int li = 0;
  for (int blk = 0; blk < 2; blk++){
    unsigned short* saved = cur;
    unsigned short* ins[3]  = {cur, f1, f2};
    unsigned short* outs[3] = {f1, f2, f1};
    for (int j = 0; j < 3; j++){
      unsigned short* X = ins[j]; unsigned short* Yo = outs[j];
      // msg: [N,80] @ [96->160] (both edge types fused in cols)
      wgemm<64,3,3><<<dim3(1024,1), 256, 0, stream>>>(
          X, 80, 80,  nullptr, 0, 0,  nullptr, 0, 0,
          BtA + li*15360, 96, biasA + li*160,
          P2, 160, N, 10, 0);
      k_aggregate<<<(N+15)/16, 256, 0, stream>>>(off, edata, P2, 160, 80, agg, 80, N, 1);
      // upd: [N,80|80] @ [160->80]
      wgemm<64,5,2><<<dim3(1024,1), 256, 0, stream>>>(
          X, 80, 80,  agg, 80, 80,  nullptr, 0, 0,
          BtA + 92160 + li*12800, 160, biasA + 960 + li*80,
          Yo, 80, N, 5, 0);
      li++;
    }
    // AR msg: [N,80|80] @ [160->320], gelu; y splits 20 col tiles into 12+8
    wgemm<64,5,3><<<dim3(512,2), 256, 0, stream>>>(
        saved, 80, 80,  f1, 80, 80,  nullptr, 0, 0,
        BtA + 168960 + blk*51200, 160, biasA + 1440 + blk*320,
        P2, 320, N, 20, 1 /*gelu*/);
    k_aggregate<<<(N+7)/8, 256, 0, stream>>>(off, edata, P2, 320, 160, agg, 160, N, 2);
    // AR upd: [N,80|80|160] @ [320->80], tanh; 32-row tiles (K=320 LDS)
    wgemm<32,10,2><<<dim3(1024,1), 256, 0, stream>>>(
        saved, 80, 80,  f1, 80, 80,  agg, 160, 160,
        BtA + 271360 + blk*25600, 320, biasA + 2080 + blk*80,
        f2, 80, N, 5, 2 /*tanh*/);
    unsigned short* t3 = cur; cur = f2; f2 = t3;
  }

  k_head<<<1, 640, 0, stream>>>(cur, entry, W1, b1, W2, b2, out);
}